// Round 8
// baseline (140.177 us; speedup 1.0000x reference)
//
#include <hip/hip_runtime.h>
#include <hip/hip_bf16.h>
#include <math.h>

typedef short short8 __attribute__((ext_vector_type(8)));
typedef float f32x16 __attribute__((ext_vector_type(16)));

#define BB 16
#define CC 256
#define HH 64
#define WW 64
#define HWX 4096
#define DD 4
#define KD 9
#define KK 81
#define GR 4          // h-rows (groups) per block
#define NSLOT 12      // B rows staged: h0-4 .. h0+7

__device__ __forceinline__ short bf16c(float x) {
    __hip_bfloat16 h = __float2bfloat16(x);
    return *reinterpret_cast<short*>(&h);
}

// 8 strided loads: c = c0..c0+7 at w = l. row and c0 are wave-uniform
// (c0 derived from readfirstlane'd wave id) -> s-base + v(l*4) addressing.
__device__ __forceinline__ void b_issue8(const float* __restrict__ row,
                                         int c0, int l, float* v) {
    #pragma unroll
    for (int j = 0; j < 8; ++j)
        v[j] = row[(size_t)(c0 + j) * HWX + l];
}

// cvt + one swizzled ds_write_b128; returns sumsq partial
__device__ __forceinline__ float b_commit8(const float* v, unsigned short* bufp,
                                           int c0, int l) {
    float ss = 0.f;
    #pragma unroll
    for (int j = 0; j < 8; ++j) ss += v[j] * v[j];
    short8 st;
    #pragma unroll
    for (int j = 0; j < 8; ++j) st[j] = bf16c(v[j]);
    const int byte = (l * 512 + c0 * 2) ^ ((l & 31) << 4);
    *(short8*)((char*)bufp + byte) = st;
    return ss;
}

__global__ __launch_bounds__(1024) void corr_mfma(
    const float* __restrict__ fA, const float* __restrict__ fB,
    float* __restrict__ out)
{
    __shared__ __attribute__((aligned(16))) unsigned short buf[2][WW * CC]; // 64 KB
    __shared__ float red[GR][2][KD][WW + 1];   // 18.7 KB, padded scatter
    __shared__ float part[2][16 * WW];         // 8 KB sumsq partials ([1] aliases A partials)

    const int bid = blockIdx.x;                       // 256 blocks = 1/CU
    const int swzb = (bid & 7) * 32 + (bid >> 3);     // XCD-bijective (256%8==0)
    const int b = swzb >> 4, jr = swzb & 15;
    const int h0 = 4 * jr;

    const int tid = threadIdx.x;
    const int l = tid & 63;
    const int wvu = __builtin_amdgcn_readfirstlane(tid >> 6);  // wave id, SGPR
    const int g = wvu >> 2;                // group: row h0+g
    const int q = wvu & 3;                 // quadrant wave within group
    const int hg = h0 + g;
    const int ti = q >> 1, tj = q & 1;
    const int ml = l & 31, kg = l >> 5;
    const int m = ti * 32 + ml;            // A row (w)
    const int n = tj * 32 + ml;            // B row (w')

    // ---- A prologue pass 1: sumsq -> invA (per group row) ----
    const float* Abase = fA + (size_t)b * CC * HWX + hg * WW;
    {
        float ss = 0.f;
        #pragma unroll
        for (int r = 0; r < 8; ++r) {
            float v[8];
            #pragma unroll
            for (int j = 0; j < 8; ++j) v[j] = Abase[(size_t)(q * 64 + r * 8 + j) * HWX + l];
            #pragma unroll
            for (int j = 0; j < 8; ++j) ss += v[j] * v[j];
        }
        part[1][wvu * 64 + l] = ss;        // aliases B partials (rewritten later)
    }
    __syncthreads();
    float iaA;
    {
        const int gb = g * 4;
        iaA = 1.f / fmaxf(sqrtf(part[1][(gb + 0) * 64 + l] + part[1][(gb + 1) * 64 + l]
                              + part[1][(gb + 2) * 64 + l] + part[1][(gb + 3) * 64 + l]), 1e-12f);
    }
    for (int i = tid; i < GR * 2 * KD * (WW + 1); i += 1024) ((float*)red)[i] = 0.f;

    // ---- A stage + frag hoist, two rounds (4 groups share 2 buffers) ----
    short8 afr[16];
    #pragma unroll
    for (int round = 0; round < 2; ++round) {
        if ((g >> 1) == round) {           // scalar branch: groups 2r, 2r+1
            #pragma unroll
            for (int r = 0; r < 8; ++r) {
                const int c = q * 64 + r * 8;
                float v[8]; short8 st;
                #pragma unroll
                for (int j = 0; j < 8; ++j) v[j] = Abase[(size_t)(c + j) * HWX + l];
                #pragma unroll
                for (int j = 0; j < 8; ++j) st[j] = bf16c(v[j] * iaA);
                const int byte = (l * 512 + c * 2) ^ ((l & 31) << 4);
                *(short8*)((char*)buf[g & 1] + byte) = st;
            }
        }
        __syncthreads();
        if ((g >> 1) == round) {
            #pragma unroll
            for (int s = 0; s < 16; ++s) {
                const int byte = (m * 512 + s * 32 + kg * 16) ^ ((m & 31) << 4);
                afr[s] = *(const short8*)((const char*)buf[g & 1] + byte);
            }
        }
        __syncthreads();
    }

    // ---- B pipeline: 12 shared row-slots, ONE barrier per slot ----
    const float* fBb = fB + (size_t)b * CC * HWX;
    {   // prologue: stage slot 0 (row h0-4) into buf[0]
        const int hb0 = h0 - DD;
        if ((unsigned)hb0 < HH) {
            const float* row = fBb + (size_t)hb0 * WW;
            float v[8];
            b_issue8(row, wvu * 16, l, v);
            float ss = b_commit8(v, buf[0], wvu * 16, l);
            b_issue8(row, wvu * 16 + 8, l, v);
            ss += b_commit8(v, buf[0], wvu * 16 + 8, l);
            part[0][wvu * 64 + l] = ss;
        }
    }
    __syncthreads();

    for (int r = 0; r < NSLOT; ++r) {
        const int cur = r & 1;
        const int hb = h0 - DD + r;
        const bool vcur = (unsigned)hb < HH;
        const bool vnext = (r + 1 < NSLOT) && ((unsigned)(hb + 1) < HH);
        const float* nrow = fBb + (size_t)(hb + 1) * WW;
        const int dy = r - g;
        const bool dyv = (dy >= 0 && dy < KD);
        const bool comp = dyv && vcur;

        // 1. issue half0 of next row (flies under store + MFMA octet 1)
        float v[8];
        if (vnext) b_issue8(nrow, wvu * 16, l, v);

        // 2. store previous slot's red (parity cur^1)
        if (r >= 1) {
            const int dyp = (r - 1) - g;
            if (dyp >= 0 && dyp < KD) {
                const int tid2 = q * 64 + l;
                float* ob = out + (((size_t)b * KK + dyp * KD) * HH + hg) * WW;
                for (int i = tid2; i < KD * WW; i += 256)
                    ob[(size_t)(i >> 6) * HWX + (i & 63)] = red[g][cur ^ 1][i >> 6][i & 63];
            }
        }

        // 3. MFMA octet 1
        f32x16 acc;
        if (comp) {
            #pragma unroll
            for (int i = 0; i < 16; ++i) acc[i] = 0.f;
            __builtin_amdgcn_s_setprio(1);
            #pragma unroll
            for (int s = 0; s < 8; ++s) {
                const int byte = (n * 512 + s * 32 + kg * 16) ^ ((n & 31) << 4);
                short8 bfr = *(const short8*)((const char*)buf[cur] + byte);
                acc = __builtin_amdgcn_mfma_f32_32x32x16_bf16(afr[s], bfr, acc, 0, 0, 0);
            }
            __builtin_amdgcn_s_setprio(0);
        }

        // 4. commit half0 (vmcnt covered by octet 1), issue half1
        float ssn = 0.f;
        if (vnext) {
            ssn = b_commit8(v, buf[cur ^ 1], wvu * 16, l);
            b_issue8(nrow, wvu * 16 + 8, l, v);
        }

        // 5. MFMA octet 2 + epilogue scatter
        if (comp) {
            __builtin_amdgcn_s_setprio(1);
            #pragma unroll
            for (int s = 8; s < 16; ++s) {
                const int byte = (n * 512 + s * 32 + kg * 16) ^ ((n & 31) << 4);
                short8 bfr = *(const short8*)((const char*)buf[cur] + byte);
                acc = __builtin_amdgcn_mfma_f32_32x32x16_bf16(afr[s], bfr, acc, 0, 0, 0);
            }
            __builtin_amdgcn_s_setprio(0);
            float sB = 0.f;
            #pragma unroll
            for (int w16 = 0; w16 < 16; ++w16) sB += part[cur][w16 * 64 + n];
            const float ibn = 1.f / fmaxf(sqrtf(sB), 1e-12f);
            #pragma unroll
            for (int rr = 0; rr < 16; ++rr) {
                // D layout (m74/m101): col = lane&31 (=w'), row = (rr&3)+8*(rr>>2)+4*kg
                const int w = ti * 32 + (rr & 3) + 8 * (rr >> 2) + 4 * kg;
                const int dx = n - w + 4;
                if (dx >= 0 && dx < KD) red[g][cur][dx][w] = acc[rr] * ibn;
            }
        } else if (dyv) {
            #pragma unroll
            for (int rr = 0; rr < 16; ++rr) {
                const int w = ti * 32 + (rr & 3) + 8 * (rr >> 2) + 4 * kg;
                const int dx = n - w + 4;
                if (dx >= 0 && dx < KD) red[g][cur][dx][w] = 0.f;
            }
        }

        // 6. commit half1, publish sumsq partial
        if (vnext) {
            ssn += b_commit8(v, buf[cur ^ 1], wvu * 16 + 8, l);
            part[cur ^ 1][wvu * 64 + l] = ssn;
        }
        __syncthreads();
    }

    // final store for slot NSLOT-1
    {
        const int dyp = (NSLOT - 1) - g;
        if (dyp >= 0 && dyp < KD) {
            const int tid2 = q * 64 + l;
            float* ob = out + (((size_t)b * KK + dyp * KD) * HH + hg) * WW;
            for (int i = tid2; i < KD * WW; i += 256)
                ob[(size_t)(i >> 6) * HWX + (i & 63)] = red[g][(NSLOT - 1) & 1][i >> 6][i & 63];
        }
    }
}

extern "C" void kernel_launch(void* const* d_in, const int* in_sizes, int n_in,
                              void* d_out, int out_size, void* d_ws, size_t ws_size,
                              hipStream_t stream) {
    const float* fA = (const float*)d_in[0];
    const float* fB = (const float*)d_in[1];
    float* outp = (float*)d_out;
    corr_mfma<<<dim3(BB * HH / GR), 1024, 0, stream>>>(fA, fB, outp);
}

// Round 9
// 66.210 us; speedup vs baseline: 2.1172x; 2.1172x over previous
//
#include <hip/hip_runtime.h>
#include <hip/hip_bf16.h>
#include <math.h>

typedef short short8 __attribute__((ext_vector_type(8)));
typedef float f32x16 __attribute__((ext_vector_type(16)));

#define BB 16
#define CC 256
#define HH 64
#define WW 64
#define HWX 4096
#define DD 4
#define KD 9
#define KK 81
#define NSLOT 10

__device__ __forceinline__ short bf16c(float x) {
    __hip_bfloat16 h = __float2bfloat16(x);
    return *reinterpret_cast<short*>(&h);
}

// issue 32 strided global loads for one B row chunk (lane: w=l, c=wv*32..+31)
__device__ __forceinline__ void b_issue32(const float* __restrict__ row,
                                          int c0, int l, float* v) {
    #pragma unroll
    for (int j = 0; j < 32; ++j)
        v[j] = row[(size_t)(c0 + j) * HWX + l];
}

// cvt + 4 swizzled ds_write_b128 + sumsq partial for the whole 32-ch chunk
__device__ __forceinline__ void b_commit32(const float* v, unsigned short* bufp,
                                           float* partp, int c0, int wvslot, int l) {
    float ss = 0.f;
    #pragma unroll
    for (int j = 0; j < 32; ++j) ss += v[j] * v[j];
    #pragma unroll
    for (int ch = 0; ch < 4; ++ch) {
        short8 st;
        #pragma unroll
        for (int j = 0; j < 8; ++j) st[j] = bf16c(v[ch * 8 + j]);
        const int c = c0 + ch * 8;
        const int byte = (l * 512 + c * 2) ^ ((l & 31) << 4);
        *(short8*)((char*)bufp + byte) = st;
    }
    partp[wvslot * 64 + l] = ss;
}

__global__ __launch_bounds__(512) void corr_mfma(
    const float* __restrict__ fA, const float* __restrict__ fB,
    float* __restrict__ out)
{
    __shared__ __attribute__((aligned(16))) unsigned short buf[2][WW * CC]; // 64 KB
    __shared__ float red[2][2][KD][WW + 1];   // [group][parity], padded scatter
    __shared__ float part[2][8 * WW];         // [parity] sumsq partials ([1] aliases A partials)

    const int bid = blockIdx.x;                       // 512 blocks
    const int swzb = (bid & 7) * 64 + (bid >> 3);     // XCD-bijective (512%8==0)
    const int b = swzb >> 5, jr = swzb & 31;
    const int h0 = 2 * jr;

    const int tid = threadIdx.x;
    const int wv = tid >> 6, l = tid & 63;
    const int g = wv >> 2;                 // group: row h0+g
    const int q = wv & 3;                  // quadrant wave within group
    const int hg = h0 + g;
    const int ti = q >> 1, tj = q & 1;
    const int ml = l & 31, kg = l >> 5;
    const int m = ti * 32 + ml;            // A row (w)
    const int n = tj * 32 + ml;            // B row (w')

    // ---- A prologue (two-pass: sumsq, then invA-folded bf16 stage) ----
    const float* Abase = fA + (size_t)b * CC * HWX + hg * WW;
    {
        float ss = 0.f;
        #pragma unroll
        for (int r = 0; r < 8; ++r) {
            float v[8];
            #pragma unroll
            for (int j = 0; j < 8; ++j) v[j] = Abase[(size_t)(q * 64 + r * 8 + j) * HWX + l];
            #pragma unroll
            for (int j = 0; j < 8; ++j) ss += v[j] * v[j];
        }
        part[1][wv * 64 + l] = ss;     // partA aliases part[1] (rewritten later)
    }
    __syncthreads();
    float iaA;
    {
        float s = part[1][(g * 4 + 0) * 64 + l] + part[1][(g * 4 + 1) * 64 + l]
                + part[1][(g * 4 + 2) * 64 + l] + part[1][(g * 4 + 3) * 64 + l];
        iaA = 1.f / fmaxf(sqrtf(s), 1e-12f);
    }
    for (int i = tid; i < 2 * 2 * KD * (WW + 1); i += 512) ((float*)red)[i] = 0.f;
    #pragma unroll
    for (int r = 0; r < 8; ++r) {
        const int c = q * 64 + r * 8;
        float v[8]; short8 st;
        #pragma unroll
        for (int j = 0; j < 8; ++j) v[j] = Abase[(size_t)(c + j) * HWX + l];
        #pragma unroll
        for (int j = 0; j < 8; ++j) st[j] = bf16c(v[j] * iaA);
        const int byte = (l * 512 + c * 2) ^ ((l & 31) << 4);
        *(short8*)((char*)buf[g] + byte) = st;
    }
    __syncthreads();
    short8 afr[16];
    #pragma unroll
    for (int s = 0; s < 16; ++s) {
        const int byte = (m * 512 + s * 32 + kg * 16) ^ ((m & 31) << 4);
        afr[s] = *(const short8*)((const char*)buf[g] + byte);
    }
    __syncthreads();      // hoist reads complete before buf[0] is restaged

    // ---- B pipeline: 10 shared row-slots, ONE barrier per slot ----
    const float* fBb = fB + (size_t)b * CC * HWX;
    {   // prologue: stage slot 0 into buf[0]
        const int hb0 = h0 - DD;
        if ((unsigned)hb0 < HH) {
            float v[32];
            b_issue32(fBb + (size_t)hb0 * WW, wv * 32, l, v);
            b_commit32(v, buf[0], part[0], wv * 32, wv, l);
        }
    }
    __syncthreads();

    for (int r = 0; r < NSLOT; ++r) {
        const int cur = r & 1;
        const int hb = h0 - DD + r;
        const bool vcur = (unsigned)hb < HH;
        const bool vnext = (r + 1 < NSLOT) && ((unsigned)(hb + 1) < HH);
        const int dy = r - g;
        const bool dyv = (dy >= 0 && dy < KD);
        const bool comp = dyv && vcur;

        // 1. issue ALL next-row loads (fly under store + 16 MFMA + sB reduce)
        float v[32];
        if (vnext) b_issue32(fBb + (size_t)(hb + 1) * WW, wv * 32, l, v);

        // 2. store previous slot's red (parity cur^1)
        if (r >= 1) {
            const int dyp = (r - 1) - g;
            if (dyp >= 0 && dyp < KD) {
                const int tid2 = q * 64 + l;
                float* ob = out + (((size_t)b * KK + dyp * KD) * HH + hg) * WW;
                for (int i = tid2; i < KD * WW; i += 256)
                    ob[(size_t)(i >> 6) * HWX + (i & 63)] = red[g][cur ^ 1][i >> 6][i & 63];
            }
        }

        // 3. all 16 MFMA + epilogue arithmetic
        if (comp) {
            f32x16 acc;
            #pragma unroll
            for (int i = 0; i < 16; ++i) acc[i] = 0.f;
            __builtin_amdgcn_s_setprio(1);
            #pragma unroll
            for (int s = 0; s < 16; ++s) {
                const int byte = (n * 512 + s * 32 + kg * 16) ^ ((n & 31) << 4);
                short8 bfr = *(const short8*)((const char*)buf[cur] + byte);
                acc = __builtin_amdgcn_mfma_f32_32x32x16_bf16(afr[s], bfr, acc, 0, 0, 0);
            }
            __builtin_amdgcn_s_setprio(0);
            float sB = 0.f;
            #pragma unroll
            for (int qq = 0; qq < 8; ++qq) sB += part[cur][qq * 64 + n];
            const float ibn = 1.f / fmaxf(sqrtf(sB), 1e-12f);
            #pragma unroll
            for (int rr = 0; rr < 16; ++rr) {
                // D layout (m74/m101): col = lane&31 (=w'), row = (rr&3)+8*(rr>>2)+4*kg
                const int w = ti * 32 + (rr & 3) + 8 * (rr >> 2) + 4 * kg;
                const int dx = n - w + 4;
                if (dx >= 0 && dx < KD) red[g][cur][dx][w] = acc[rr] * ibn;
            }
        } else if (dyv) {
            #pragma unroll
            for (int rr = 0; rr < 16; ++rr) {
                const int w = ti * 32 + (rr & 3) + 8 * (rr >> 2) + 4 * kg;
                const int dx = n - w + 4;
                if (dx >= 0 && dx < KD) red[g][cur][dx][w] = 0.f;
            }
        }

        // 4. single late commit of the staged row (one vmcnt point per slot)
        if (vnext)
            b_commit32(v, buf[cur ^ 1], part[cur ^ 1], wv * 32, wv, l);
        __syncthreads();
    }

    // final store for slot NSLOT-1
    {
        const int dyp = (NSLOT - 1) - g;
        if (dyp >= 0 && dyp < KD) {
            const int tid2 = q * 64 + l;
            float* ob = out + (((size_t)b * KK + dyp * KD) * HH + hg) * WW;
            for (int i = tid2; i < KD * WW; i += 256)
                ob[(size_t)(i >> 6) * HWX + (i & 63)] = red[g][(NSLOT - 1) & 1][i >> 6][i & 63];
        }
    }
}

extern "C" void kernel_launch(void* const* d_in, const int* in_sizes, int n_in,
                              void* d_out, int out_size, void* d_ws, size_t ws_size,
                              hipStream_t stream) {
    const float* fA = (const float*)d_in[0];
    const float* fB = (const float*)d_in[1];
    float* outp = (float*)d_out;
    corr_mfma<<<dim3(BB * HH / 2), 512, 0, stream>>>(fA, fB, outp);
}